// Round 1
// baseline (45.469 us; speedup 1.0000x reference)
//
#include <hip/hip_runtime.h>

// y[b,f] = W0[f] + W1[f] * x[b,f]
// B=4096, F=8192, fp32 in/out. Pure memory-bound elementwise op.
// float4 vectorized, grid-stride, W0/W1 (32 KiB each) stay L1/L2 resident.

__global__ void __launch_bounds__(256)
scl_kernel(const float4* __restrict__ x,
           const float4* __restrict__ W0,
           const float4* __restrict__ W1,
           float4* __restrict__ out,
           int n4, int f4mask) {
    int stride = gridDim.x * blockDim.x;
    for (int i = blockIdx.x * blockDim.x + threadIdx.x; i < n4; i += stride) {
        int f = i & f4mask;              // F/4 is a power of two (2048)
        float4 xv = x[i];
        float4 w0 = W0[f];
        float4 w1 = W1[f];
        float4 o;
        o.x = fmaf(w1.x, xv.x, w0.x);
        o.y = fmaf(w1.y, xv.y, w0.y);
        o.z = fmaf(w1.z, xv.z, w0.z);
        o.w = fmaf(w1.w, xv.w, w0.w);
        out[i] = o;
    }
}

extern "C" void kernel_launch(void* const* d_in, const int* in_sizes, int n_in,
                              void* d_out, int out_size, void* d_ws, size_t ws_size,
                              hipStream_t stream) {
    const float4* x  = (const float4*)d_in[0];   // (B,F) = (4096, 8192)
    const float4* W0 = (const float4*)d_in[1];   // (F,)
    const float4* W1 = (const float4*)d_in[2];   // (F,)
    float4* out = (float4*)d_out;

    const int F = in_sizes[1];          // 8192
    const int n4 = out_size / 4;        // 33,554,432 / 4 = 8,388,608
    const int f4mask = (F / 4) - 1;     // 2047

    const int block = 256;
    const int grid = 2048;              // 256 CU x 8 blocks, grid-stride

    scl_kernel<<<grid, block, 0, stream>>>(x, W0, W1, out, n4, f4mask);
}